// Round 1
// baseline (102.929 us; speedup 1.0000x reference)
//
#include <hip/hip_runtime.h>
#include <hip/hip_bf16.h>

#define BB 4
#define CIN 256      // CK == CQ == CV
#define CO 64
#define NN 576       // 24*24
#define NKC 18       // 576/32 k-chunks
#define NQT 36       // q-subtiles of 16

typedef __attribute__((ext_vector_type(8))) short short8;
typedef __attribute__((ext_vector_type(4))) float floatx4;

__device__ __forceinline__ unsigned short f2bf(float f) {
    unsigned int u = __float_as_uint(f);
    unsigned int r = (u + 0x7fffu + ((u >> 16) & 1u)) >> 16;   // RNE
    return (unsigned short)r;
}

// ------------------------------------------------------------------
// Fused x-pack + W-pack + proj GEMM + exp:
//   e[b,n,o] = exp(2*(sum_c x[b,c,n]*W[o,c] + bias[o]))
// Block = 16 n-rows x 256 c, 4 waves; wave w handles nt = w (16 o cols).
// x tile staged in LDS f32 [c][n] with pad-17 (transposed reads are
// 2-way bank aliased = free). A-frag built from LDS, B-frag (W) built
// straight from global (L2-hot after first blocks). No Xp/Wp buffers.
// grid: (36 n-tiles, 4 b, 2 z) x 256.
__global__ void __launch_bounds__(256) proj_exp_fused(
    const float* __restrict__ key, const float* __restrict__ query,
    const float* __restrict__ Wk, const float* __restrict__ Wq,
    const float* __restrict__ bk, const float* __restrict__ bq,
    float* __restrict__ ek, float* __restrict__ eq)
{
    int nt16 = blockIdx.x;       // n-tile of 16 rows, 0..35
    int b    = blockIdx.y;
    int z    = blockIdx.z;
    const float* src  = z ? query : key;
    const float* W    = z ? Wq : Wk;
    const float* bias = z ? bq : bk;
    float*       outp = z ? eq : ek;

    __shared__ float tile[256 * 17];   // [c][n], pad 17

    int t = threadIdx.x, l = t & 63, w = t >> 6;

    // stage 256c x 16n f32, coalesced (64B per c-row)
    const float* sbase = src + (size_t)b * CIN * NN + (size_t)nt16 * 16;
    #pragma unroll
    for (int i = 0; i < 4; ++i) {
        int f4  = t + i * 256;          // 0..1023
        int c   = f4 >> 2;
        int col = (f4 & 3) * 4;
        float4 v = *(const float4*)(sbase + (size_t)c * NN + col);
        float* d = &tile[c * 17 + col];
        d[0] = v.x; d[1] = v.y; d[2] = v.z; d[3] = v.w;
    }
    __syncthreads();

    int nt = w;                          // o-subtile per wave
    int m  = l & 15;                     // n row within tile
    int o  = nt * 16 + (l & 15);
    floatx4 acc = {0.f, 0.f, 0.f, 0.f};
    #pragma unroll
    for (int kc = 0; kc < 8; ++kc) {
        int cb = kc * 32 + (l >> 4) * 8;
        // A-frag: elem j = X[n = nt16*16 + (l&15)][c = cb + j]
        short8 a;
        #pragma unroll
        for (int j = 0; j < 8; ++j)
            a[j] = (short)f2bf(tile[(cb + j) * 17 + m]);
        // B-frag: elem j = W[o][cb + j]
        const float4* p = (const float4*)(W + (size_t)o * CIN + cb);
        float4 v0 = p[0], v1 = p[1];
        short8 bfr;
        bfr[0] = (short)f2bf(v0.x); bfr[1] = (short)f2bf(v0.y);
        bfr[2] = (short)f2bf(v0.z); bfr[3] = (short)f2bf(v0.w);
        bfr[4] = (short)f2bf(v1.x); bfr[5] = (short)f2bf(v1.y);
        bfr[6] = (short)f2bf(v1.z); bfr[7] = (short)f2bf(v1.w);
        acc = __builtin_amdgcn_mfma_f32_16x16x32_bf16(a, bfr, acc, 0, 0, 0);
    }

    int n0 = nt16 * 16;
    float bv = bias[o];
    #pragma unroll
    for (int rr = 0; rr < 4; ++rr) {
        int row = (l >> 4) * 4 + rr;
        outp[((size_t)b * NN + n0 + row) * CO + o] = __expf(2.0f * (acc[rr] + bv));
    }
}

// ------------------------------------------------------------------
// attn scores + sigmoid + bf16 B-fragment pack.  (unchanged — verified)
// score(k,q) = C - sum_o 2*wf[o]/(1 + ek[k,o]*eq[q,o]),  C = sum wf + bf.
// grid: (NN/64, NN/32, BB), block 256 = 4 waves (wave w -> 8 k).
__global__ void __launch_bounds__(256, 3) attn_pack_kernel(
    const float* __restrict__ ek, const float* __restrict__ eq,
    const float* __restrict__ wf, const float* __restrict__ bfp,
    unsigned short* __restrict__ Bp)
{
    int b  = blockIdx.z;
    int k0 = blockIdx.y * 32;
    int q0 = blockIdx.x * 64;
    int t  = threadIdx.x;
    int l  = t & 63;
    int w  = __builtin_amdgcn_readfirstlane(t >> 6);

    __shared__ float eqs[64 * 65];
    __shared__ float sc[32 * 65];

    // coalesced global -> LDS (16 KB contiguous span)
    const float4* esrc = (const float4*)(eq + ((size_t)b * NN + q0) * CO);
    #pragma unroll
    for (int i = 0; i < 4; ++i) {
        int f4  = t + i * 256;                 // 0..1023
        int row = f4 >> 4, c4 = (f4 & 15) * 4;
        float4 v = esrc[f4];
        int a = row * 65 + c4;
        eqs[a + 0] = v.x; eqs[a + 1] = v.y; eqs[a + 2] = v.z; eqs[a + 3] = v.w;
    }

    float4 w2v[16];
    float C = bfp[0];
    const float4* wfp4 = (const float4*)wf;
    #pragma unroll
    for (int i = 0; i < 16; ++i) {
        float4 wv = wfp4[i];
        C += wv.x + wv.y + wv.z + wv.w;
        wv.x *= 2.0f; wv.y *= 2.0f; wv.z *= 2.0f; wv.w *= 2.0f;
        w2v[i] = wv;
    }
    __syncthreads();

    // lane l's q-row into VGPRs (2-way bank aliasing only = free)
    float4 eqv[16];
    #pragma unroll
    for (int i = 0; i < 16; ++i) {
        int a = l * 65 + i * 4;
        eqv[i].x = eqs[a]; eqv[i].y = eqs[a + 1];
        eqv[i].z = eqs[a + 2]; eqv[i].w = eqs[a + 3];
    }

    #pragma unroll 1
    for (int kk = 0; kk < 8; ++kk) {
        int k = k0 + w * 8 + kk;               // wave-uniform
        const float4* ekr = (const float4*)(ek + ((size_t)b * NN + k) * CO);
        float a0 = 0.f, a1 = 0.f, a2 = 0.f, a3 = 0.f;
        #pragma unroll
        for (int i = 0; i < 16; ++i) {
            float4 k4 = ekr[i];
            float4 e4 = eqv[i];
            float4 w4 = w2v[i];
            a0 = fmaf(w4.x, __builtin_amdgcn_rcpf(fmaf(k4.x, e4.x, 1.0f)), a0);
            a1 = fmaf(w4.y, __builtin_amdgcn_rcpf(fmaf(k4.y, e4.y, 1.0f)), a1);
            a2 = fmaf(w4.z, __builtin_amdgcn_rcpf(fmaf(k4.z, e4.z, 1.0f)), a2);
            a3 = fmaf(w4.w, __builtin_amdgcn_rcpf(fmaf(k4.w, e4.w, 1.0f)), a3);
        }
        float score = C - (a0 + a1) - (a2 + a3);
        float sg = __builtin_amdgcn_rcpf(1.0f + __expf(-score));
        sc[(w * 8 + kk) * 65 + l] = sg;
    }
    __syncthreads();

    // pack: wave w -> q-subtile w; fragment elem j = sc[(l>>4)*8+j][w*16+(l&15)]
    int col = w * 16 + (l & 15);
    int row = (l >> 4) * 8;
    uint4 o;
    o.x = (unsigned)f2bf(sc[(row + 0) * 65 + col]) | ((unsigned)f2bf(sc[(row + 1) * 65 + col]) << 16);
    o.y = (unsigned)f2bf(sc[(row + 2) * 65 + col]) | ((unsigned)f2bf(sc[(row + 3) * 65 + col]) << 16);
    o.z = (unsigned)f2bf(sc[(row + 4) * 65 + col]) | ((unsigned)f2bf(sc[(row + 5) * 65 + col]) << 16);
    o.w = (unsigned)f2bf(sc[(row + 6) * 65 + col]) | ((unsigned)f2bf(sc[(row + 7) * 65 + col]) << 16);
    size_t qt = (size_t)blockIdx.x * 4 + w;
    *(uint4*)(Bp + (((size_t)b * NQT + qt) * NKC + blockIdx.y) * 512 + l * 8) = o;
}

// ------------------------------------------------------------------
// out[b,c,q] = sum_k V[b,c,k]*attn[b,k,q] via mfma_f32_16x16x32_bf16.
// V A-fragments built on the fly from global value (L2-resident; the
// 9x qx re-read is ~21 MB from L2) — no Vp buffer.
// block 256 = 4 waves; tile 16c x 64q; wave w takes kc = w, w+4, ... then
// LDS k-split reduce. grid: (NN/64, 16, BB)
__global__ void __launch_bounds__(256) av_mfma_kernel(
    const float* __restrict__ value,
    const unsigned short* __restrict__ Bp,
    float* __restrict__ out)
{
    int b  = blockIdx.z;
    int ct = blockIdx.y;
    int qx = blockIdx.x;
    int t  = threadIdx.x;
    int l  = t & 63;
    int w  = __builtin_amdgcn_readfirstlane(t >> 6);

    floatx4 acc[4] = {{0.f,0.f,0.f,0.f},{0.f,0.f,0.f,0.f},
                      {0.f,0.f,0.f,0.f},{0.f,0.f,0.f,0.f}};

    // lane's V row/k-phase base: c = ct*16 + (l&15), k = kc*32 + (l>>4)*8 + j
    const float* vb = value + ((size_t)b * CIN + ct * 16 + (l & 15)) * NN + (l >> 4) * 8;
    const unsigned short* bbase = Bp + ((size_t)b * NQT + (size_t)qx * 4) * NKC * 512 + l * 8;

    for (int kc = w; kc < NKC; kc += 4) {
        const float4* p = (const float4*)(vb + kc * 32);
        float4 v0 = p[0], v1 = p[1];
        short8 a;
        a[0] = (short)f2bf(v0.x); a[1] = (short)f2bf(v0.y);
        a[2] = (short)f2bf(v0.z); a[3] = (short)f2bf(v0.w);
        a[4] = (short)f2bf(v1.x); a[5] = (short)f2bf(v1.y);
        a[6] = (short)f2bf(v1.z); a[7] = (short)f2bf(v1.w);
        #pragma unroll
        for (int qt = 0; qt < 4; ++qt) {
            short8 bq = *(const short8*)(bbase + ((size_t)qt * NKC + kc) * 512);
            acc[qt] = __builtin_amdgcn_mfma_f32_16x16x32_bf16(a, bq, acc[qt], 0, 0, 0);
        }
    }

    __shared__ float red[4][64][17];
    #pragma unroll
    for (int qt = 0; qt < 4; ++qt)
        #pragma unroll
        for (int r = 0; r < 4; ++r)
            red[w][l][qt * 4 + r] = acc[qt][r];
    __syncthreads();

    int q = qx * 64 + w * 16 + (l & 15);
    #pragma unroll
    for (int r = 0; r < 4; ++r) {
        float s = red[0][l][w * 4 + r] + red[1][l][w * 4 + r]
                + red[2][l][w * 4 + r] + red[3][l][w * 4 + r];
        int c = ct * 16 + (l >> 4) * 4 + r;
        out[((size_t)b * CIN + c) * NN + q] = s;
    }
}

// ------------------------------------------------------------------
extern "C" void kernel_launch(void* const* d_in, const int* in_sizes, int n_in,
                              void* d_out, int out_size, void* d_ws, size_t ws_size,
                              hipStream_t stream) {
    const float* key   = (const float*)d_in[0];
    const float* query = (const float*)d_in[1];
    const float* value = (const float*)d_in[2];
    const float* Wk    = (const float*)d_in[3];
    const float* bk    = (const float*)d_in[4];
    const float* Wq    = (const float*)d_in[5];
    const float* bq    = (const float*)d_in[6];
    const float* wf    = (const float*)d_in[7];
    const float* bf    = (const float*)d_in[8];
    float* out = (float*)d_out;

    float* ws = (float*)d_ws;
    float* ek = ws;                                        // 147456 f
    float* eq = ek + (size_t)BB * NN * CO;                 // 147456 f
    unsigned short* Bp = (unsigned short*)(eq + (size_t)BB * NN * CO);
    // Bp: 4*36*18*512 us = 1.33 MB; total ws ~2.5 MB

    dim3 gp(NN / 16, BB, 2);
    proj_exp_fused<<<gp, 256, 0, stream>>>(key, query, Wk, Wq, bk, bq, ek, eq);

    dim3 ga(NN / 64, NN / 32, BB);
    attn_pack_kernel<<<ga, 256, 0, stream>>>(ek, eq, wf, bf, Bp);

    dim3 gm(NN / 64, 16, BB);
    av_mfma_kernel<<<gm, 256, 0, stream>>>(value, Bp, out);
}